// Round 6
// baseline (224.829 us; speedup 1.0000x reference)
//
#include <hip/hip_runtime.h>

#define BZ    167              // grid3d_index dims 0/1 (SIZE + 2*MARGIN)
#define BZ2   83               // BZ/2
#define NX    84               // BZ/2 + 1  (last axis)
#define NCELL (BZ * BZ * NX)   // 2,342,676 cells
#define SYC   NX               // +dy stride in cells
#define SZC   (NX * BZ)        // +dz stride in cells
#define NXC   81               // 2D coord grid x extent (SIZE/2+1)
#define NYC   161              // 2D coord grid y extent (SIZE)
#define NTX   21               // ceil(81/4)  tiles in x
#define NTZ   11               // ceil(ceil(161/4)/4) = blockIdx.z extent
#define NBX   51               // ceil(13041/256) blocks/batch (fallback tiers)

// ---- bf16 helpers (round-to-nearest-even pack, free unpack) ----
static __device__ __forceinline__ unsigned f2bf(float f) {
    unsigned u = __float_as_uint(f);
    return (u + 0x7FFFu + ((u >> 16) & 1u)) >> 16;
}
static __device__ __forceinline__ float bf_lo(unsigned u) {
    return __uint_as_float(u << 16);
}
static __device__ __forceinline__ float bf_hi(unsigned u) {
    return __uint_as_float(u & 0xFFFF0000u);
}

// ---- f16 pair helpers (for v_dot2_f32_f16 path) ----
typedef _Float16 h2 __attribute__((ext_vector_type(2)));
static __device__ __forceinline__ h2 u2h(unsigned u) {
    union { unsigned u; h2 h; } x; x.u = u; return x.h;
}
static __device__ __forceinline__ unsigned f2h2(float a, float b) {
    union { h2 h; unsigned u; } x;
    x.h.x = (_Float16)a; x.h.y = (_Float16)b;
    return x.u;
}

// ---- fused pre-pass: pack weights fp32->f16 pairs ALONG INPUT DIM (so the
// main kernel's inner loop is v_dot2_f32_f16: 2 MACs/instr, no unpack ops),
// build the z-paired metadata garrD[cell] = (j,bias)@cell || @(cell+SZ), and
// pack input to f16 pairs (B*4 u32).  Weight record layout per j (8 u32):
//   u[2a]   = {f16 w[2a][0], f16 w[2a+1][0]}   (output c=0, dims 2a,2a+1)
//   u[2a+1] = {f16 w[2a][1], f16 w[2a+1][1]}   (output c=1)
// Lane h reads uint4 at j*8+h*4 = dims 4h..4h+3, both outputs. ----
__global__ __launch_bounds__(256) void pack_allh(
    const float4* __restrict__ wsrc, uint2* __restrict__ wdst, int nw4, int nbw,
    const int* __restrict__ grid, const float* __restrict__ bias,
    int4* __restrict__ garrD, int ncell, int nbg,
    const float* __restrict__ input, unsigned* __restrict__ inpk, int nin)
{
    const int bid = (int)blockIdx.x;
    if (bid < nbw) {
        const int i = bid * 256 + threadIdx.x;
        if (i >= nw4) return;
        // float4 i covers w[2a..2a+1][0..1]: (w[2a][0], w[2a][1], w[2a+1][0], w[2a+1][1])
        const float4 v = wsrc[i];
        wdst[i] = make_uint2(f2h2(v.x, v.z), f2h2(v.y, v.w));
    } else if (bid < nbw + nbg) {
        const int i = (bid - nbw) * 256 + threadIdx.x;
        if (i >= ncell) return;
        const int j0 = grid[i];
        const int j1 = (i + SZC < ncell) ? grid[i + SZC] : -1;
        unsigned b0 = 0u, b1 = 0u;
        if (j0 >= 0)
            b0 = f2bf(bias[2 * j0]) | (f2bf(bias[2 * j0 + 1]) << 16);
        if (j1 >= 0)
            b1 = f2bf(bias[2 * j1]) | (f2bf(bias[2 * j1 + 1]) << 16);
        garrD[i] = make_int4(j0, (int)b0, j1, (int)b1);
    } else {
        const int i = (bid - nbw - nbg) * 256 + threadIdx.x;
        if (i >= nin) return;                  // nin = B*4
        const int b = i >> 2, k = i & 3;
        inpk[i] = f2h2(input[b * 8 + 2 * k], input[b * 8 + 2 * k + 1]);
    }
}

// ========= main kernel: quarter-lane, 4x4 tiles, f16 dot2 inner loop =========
// R5 post-mortem: dur 82.4us with VALUBusy 73% (~60us VALU) — VALU is the
// co-wall.  This round keeps the R5 memory structure EXACTLY (same garrD,
// same record addresses, same tile mapping => same line-touches) and cuts
// VALU ~40%:
//   * inner loop per corner: 4 v_dot2_f32_f16 + 2 fma + 2 sel (was 8 unpack +
//     8 fma + selects) — weights/input pre-packed as f16 pairs (f16 has 10
//     mantissa bits vs bf16's 8 -> absmax should IMPROVE ~4x)
//   * 3D grid (b, tx, tz): batch from blockIdx.x (x-fastest dispatch
//     reproduces XCD batch striping), tile coords via shifts — kills the
//     magic-division by NTX
//   * input as one uniform 8B load of pre-packed f16 pairs
__global__ __launch_bounds__(256, 4) void svr_dot(
    const unsigned* __restrict__ inpk,    // (B, 4) f16-pair input
    const unsigned* __restrict__ wpk,     // (W, 8) u32 = 16 f16 (dot2 layout)
    const int4*     __restrict__ garrD,   // (NCELL): z-paired (j, bias bf16x2)
    const float*    __restrict__ rot,     // (B, 3, 3)
    const float*    __restrict__ coord,   // (P, 2)
    const int*      __restrict__ max_r,
    float*          __restrict__ out,     // (B, P, 2)
    int P)
{
    const int b    = (int)blockIdx.x;          // batch (x-fastest -> XCD stripe)
    const int lane = threadIdx.x & 63;
    const int wid  = threadIdx.x >> 6;         // wave in block = tile-y sub
    const int ty   = (int)blockIdx.z * 4 + wid;
    if (ty * 4 >= NYC) return;                 // empty tile row (uniform/wave)

    const int q    = lane & 3;                 // quad lane
    const int h    = q & 1;                    // input half
    const int dxl  = q >> 1;                   // this lane's corner dx
    const int sub  = lane >> 2;                // point within 4x4 tile
    const int px   = (int)blockIdx.y * 4 + (sub & 3);
    const int py   = ty * 4 + (sub >> 2);
    if (px >= NXC || py >= NYC) return;        // edge tiles: excess lanes exit
    const int p    = py * NXC + px;

    const float2 xy = *(const float2*)(coord + 2 * p);
    const float x = xy.x, y = xy.y;

    const int mr = min(max_r[0], (BZ - 6) / 2);
    const bool valid = (x * x + y * y) <= (float)(mr * mr);

    float2* o = (float2*)(out + ((size_t)b * P + p) * 2);
    if (!valid) {
        if (q == 0) *o = make_float2(0.f, 0.f);
        return;
    }

    const float* R = rot + b * 9;              // block-uniform -> scalar loads
    float cx = fmaf(R[1], y, R[0] * x);
    float cy = fmaf(R[4], y, R[3] * x);
    float cz = fmaf(R[7], y, R[6] * x);

    float sgn = 1.f;
    if (cx < 0.f) { cx = -cx; cy = -cy; cz = -cz; sgn = -1.f; }

    const float fx = floorf(cx), fy = floorf(cy), fz = floorf(cz);
    const float tx = cx - fx, ty2 = cy - fy, tz = cz - fz;
    const int ix = (int)fx;
    const int iy = (int)fy + BZ2;
    const int iz = (int)fz + BZ2;

    // ---- 2 z-paired metadata gathers (dx folded into address) ----
    const int base0 = (iz * BZ + iy) * NX + ix + dxl;
    const int4 Gd0 = garrD[base0];         // .xy=(dy0,dz0)  .zw=(dy0,dz1)
    const int4 Gd1 = garrD[base0 + SYC];   // .xy=(dy1,dz0)  .zw=(dy1,dz1)

    // this lane's half of input[b] as f16 pairs (uniform 8B load)
    const uint2 ihu = *(const uint2*)(inpk + b * 4 + h * 2);
    const h2 ihp0 = u2h(ihu.x);            // dims 4h, 4h+1
    const h2 ihp1 = u2h(ihu.y);            // dims 4h+2, 4h+3

    // per-lane corner weights: fixed dx factor x per-i (dy,dz) factor
    const float wxd = dxl ? tx : 1.f - tx;
    float wyz[4];                               // i: 0=(dy0,dz0) 1=(dy1,dz0)
    wyz[0] = (1.f - ty2) * (1.f - tz);          //    2=(dy0,dz1) 3=(dy1,dz1)
    wyz[1] = ty2 * (1.f - tz);
    wyz[2] = (1.f - ty2) * tz;
    wyz[3] = ty2 * tz;

    int jraw[4]; unsigned bbl[4];
    jraw[0] = Gd0.x; bbl[0] = (unsigned)Gd0.y;
    jraw[1] = Gd1.x; bbl[1] = (unsigned)Gd1.y;
    jraw[2] = Gd0.z; bbl[2] = (unsigned)Gd0.w;
    jraw[3] = Gd1.z; bbl[3] = (unsigned)Gd1.w;

    int jj[4]; float wcl[4];
    #pragma unroll
    for (int i = 0; i < 4; ++i) {
        wcl[i] = (jraw[i] >= 0) ? wxd * wyz[i] : 0.f;
        jj[i]  = max(jraw[i], 0);
    }

    // ---- 4 record gathers: lane quad covers the 64B x-adjacent record pair
    uint4 U[4];
    #pragma unroll
    for (int i = 0; i < 4; ++i)
        U[i] = *(const uint4*)(wpk + (size_t)jj[i] * 8 + h * 4);

    float acc0 = 0.f, acc1 = 0.f;
    #pragma unroll
    for (int i = 0; i < 4; ++i) {
        const unsigned bb = bbl[i];
        // bias contributes once per corner: h==0 lane only
        float v0 = h ? 0.f : bf_lo(bb);
        float v1 = h ? 0.f : bf_hi(bb);
        v0 = __builtin_amdgcn_fdot2(ihp0, u2h(U[i].x), v0, false);
        v0 = __builtin_amdgcn_fdot2(ihp1, u2h(U[i].z), v0, false);
        v1 = __builtin_amdgcn_fdot2(ihp0, u2h(U[i].y), v1, false);
        v1 = __builtin_amdgcn_fdot2(ihp1, u2h(U[i].w), v1, false);
        acc0 = fmaf(wcl[i], v0, acc0);
        acc1 = fmaf(wcl[i], v1, acc1);
    }

    // combine input halves (xor 1) then dx halves (xor 2) within the quad
    acc0 += __shfl_xor(acc0, 1);
    acc1 += __shfl_xor(acc1, 1);
    acc0 += __shfl_xor(acc0, 2);
    acc1 += __shfl_xor(acc1, 2);

    if (q == 0) *o = make_float2(acc0, acc1 * sgn);
}

// ============ fallback tier 2: bf16 weights + separate bias ==================
__global__ __launch_bounds__(256) void pack_w(
    const float4* __restrict__ src, uint2* __restrict__ dst, int n)
{
    const int i = blockIdx.x * 256 + threadIdx.x;
    if (i >= n) return;
    const float4 v = src[i];
    dst[i] = make_uint2(f2bf(v.x) | (f2bf(v.y) << 16),
                        f2bf(v.z) | (f2bf(v.w) << 16));
}
__global__ __launch_bounds__(256) void pack_b(
    const float* __restrict__ bias, unsigned* __restrict__ bpk, int W)
{
    const int j = blockIdx.x * 256 + threadIdx.x;
    if (j >= W) return;
    bpk[j] = f2bf(bias[2 * j]) | (f2bf(bias[2 * j + 1]) << 16);
}

__global__ __launch_bounds__(256) void svr_bf16(
    const float* __restrict__ input, const unsigned* __restrict__ wpk,
    const unsigned* __restrict__ bpk, const int* __restrict__ grid3d,
    const float* __restrict__ rot, const float* __restrict__ coord,
    const int* __restrict__ max_r, float* __restrict__ out, int P)
{
    const int m    = blockIdx.x;
    const int xcd  = m & 7;
    const int slot = m >> 3;
    const int b    = (slot / NBX) * 8 + xcd;
    const int p    = (slot % NBX) * 256 + threadIdx.x;
    if (p >= P) return;

    const float x = coord[2 * p + 0];
    const float y = coord[2 * p + 1];
    const int mr = min(max_r[0], (BZ - 6) / 2);
    const bool valid = (x * x + y * y) <= (float)(mr * mr);
    float2* o = (float2*)(out + ((size_t)b * P + p) * 2);
    if (!valid) { *o = make_float2(0.f, 0.f); return; }

    const float* R = rot + b * 9;
    float cx = fmaf(R[1], y, R[0] * x);
    float cy = fmaf(R[4], y, R[3] * x);
    float cz = fmaf(R[7], y, R[6] * x);
    float sgn = 1.f;
    if (cx < 0.f) { cx = -cx; cy = -cy; cz = -cz; sgn = -1.f; }
    const float fx = floorf(cx), fy = floorf(cy), fz = floorf(cz);
    const float tx = cx - fx, ty = cy - fy, tz = cz - fz;
    const int ix = (int)fx, iy = (int)fy + BZ2, iz = (int)fz + BZ2;

    const float* ib = input + b * 8;
    const float in0 = ib[0], in1 = ib[1], in2 = ib[2], in3 = ib[3];
    const float in4 = ib[4], in5 = ib[5], in6 = ib[6], in7 = ib[7];

    int jj[8]; float wc[8];
    const float wx0 = 1.f - tx, wy0 = 1.f - ty, wz0 = 1.f - tz;
    #pragma unroll
    for (int dz = 0; dz < 2; ++dz)
        #pragma unroll
        for (int dy = 0; dy < 2; ++dy) {
            const int base = ((iz + dz) * BZ + (iy + dy)) * NX + ix;
            #pragma unroll
            for (int dx = 0; dx < 2; ++dx) {
                const int c = dz * 4 + dy * 2 + dx;
                const int j = grid3d[base + dx];
                const float w = (dx ? tx : wx0) * (dy ? ty : wy0) * (dz ? tz : wz0);
                wc[c] = (j >= 0) ? w : 0.f;
                jj[c] = max(j, 0);
            }
        }

    uint4 U0[8], U1[8]; unsigned BB[8];
    #pragma unroll
    for (int c = 0; c < 8; ++c) {
        const uint4* wp = (const uint4*)(wpk + (size_t)jj[c] * 8);
        U0[c] = wp[0]; U1[c] = wp[1]; BB[c] = bpk[jj[c]];
    }

    float acc0 = 0.f, acc1 = 0.f;
    #pragma unroll
    for (int c = 0; c < 8; ++c) {
        const float w = wc[c];
        float v0 = bf_lo(BB[c]), v1 = bf_hi(BB[c]);
        v0 = fmaf(in0, bf_lo(U0[c].x), v0); v1 = fmaf(in0, bf_hi(U0[c].x), v1);
        v0 = fmaf(in1, bf_lo(U0[c].y), v0); v1 = fmaf(in1, bf_hi(U0[c].y), v1);
        v0 = fmaf(in2, bf_lo(U0[c].z), v0); v1 = fmaf(in2, bf_hi(U0[c].z), v1);
        v0 = fmaf(in3, bf_lo(U0[c].w), v0); v1 = fmaf(in3, bf_hi(U0[c].w), v1);
        v0 = fmaf(in4, bf_lo(U1[c].x), v0); v1 = fmaf(in4, bf_hi(U1[c].x), v1);
        v0 = fmaf(in5, bf_lo(U1[c].y), v0); v1 = fmaf(in5, bf_hi(U1[c].y), v1);
        v0 = fmaf(in6, bf_lo(U1[c].z), v0); v1 = fmaf(in6, bf_hi(U1[c].z), v1);
        v0 = fmaf(in7, bf_lo(U1[c].w), v0); v1 = fmaf(in7, bf_hi(U1[c].w), v1);
        acc0 = fmaf(w, v0, acc0);
        acc1 = fmaf(w, v1, acc1);
    }
    *o = make_float2(acc0, acc1 * sgn);
}

// ============ fallback tier 3: direct fp32 (no workspace needed) =============
__global__ __launch_bounds__(256) void svr_fp32(
    const float* __restrict__ input, const float* __restrict__ weight,
    const float* __restrict__ bias, const int* __restrict__ grid3d,
    const float* __restrict__ rot, const float* __restrict__ coord,
    const int* __restrict__ max_r, float* __restrict__ out, int P)
{
    const int m    = blockIdx.x;
    const int xcd  = m & 7;
    const int slot = m >> 3;
    const int b    = (slot / NBX) * 8 + xcd;
    const int p    = (slot % NBX) * 256 + threadIdx.x;
    if (p >= P) return;

    const float x = coord[2 * p + 0];
    const float y = coord[2 * p + 1];
    const int mr = min(max_r[0], (BZ - 6) / 2);
    const bool valid = (x * x + y * y) <= (float)(mr * mr);
    float2* o = (float2*)(out + ((size_t)b * P + p) * 2);
    if (!valid) { *o = make_float2(0.f, 0.f); return; }

    const float* R = rot + b * 9;
    float cx = fmaf(R[1], y, R[0] * x);
    float cy = fmaf(R[4], y, R[3] * x);
    float cz = fmaf(R[7], y, R[6] * x);
    float sgn = 1.f;
    if (cx < 0.f) { cx = -cx; cy = -cy; cz = -cz; sgn = -1.f; }
    const float fx = floorf(cx), fy = floorf(cy), fz = floorf(cz);
    const float tx = cx - fx, ty = cy - fy, tz = cz - fz;
    const int ix = (int)fx, iy = (int)fy + BZ2, iz = (int)fz + BZ2;

    const float* ib = input + b * 8;
    const float in0 = ib[0], in1 = ib[1], in2 = ib[2], in3 = ib[3];
    const float in4 = ib[4], in5 = ib[5], in6 = ib[6], in7 = ib[7];

    int jj[8]; float wc[8];
    const float wx0 = 1.f - tx, wy0 = 1.f - ty, wz0 = 1.f - tz;
    #pragma unroll
    for (int dz = 0; dz < 2; ++dz)
        #pragma unroll
        for (int dy = 0; dy < 2; ++dy) {
            const int base = ((iz + dz) * BZ + (iy + dy)) * NX + ix;
            #pragma unroll
            for (int dx = 0; dx < 2; ++dx) {
                const int c = dz * 4 + dy * 2 + dx;
                const int j = grid3d[base + dx];
                const float w = (dx ? tx : wx0) * (dy ? ty : wy0) * (dz ? tz : wz0);
                wc[c] = (j >= 0) ? w : 0.f;
                jj[c] = max(j, 0);
            }
        }

    float acc0 = 0.f, acc1 = 0.f;
    #pragma unroll
    for (int c = 0; c < 8; ++c) {
        const size_t j = (size_t)jj[c];
        const float4* wp = (const float4*)(weight + j * 16);
        const float4 W0 = wp[0], W1 = wp[1], W2 = wp[2], W3 = wp[3];
        const float2 bb = *(const float2*)(bias + j * 2);
        const float w = wc[c];
        float v0 = bb.x, v1 = bb.y;
        v0 = fmaf(in0, W0.x, v0); v1 = fmaf(in0, W0.y, v1);
        v0 = fmaf(in1, W0.z, v0); v1 = fmaf(in1, W0.w, v1);
        v0 = fmaf(in2, W1.x, v0); v1 = fmaf(in2, W1.y, v1);
        v0 = fmaf(in3, W1.z, v0); v1 = fmaf(in3, W1.w, v1);
        v0 = fmaf(in4, W2.x, v0); v1 = fmaf(in4, W2.y, v1);
        v0 = fmaf(in5, W2.z, v0); v1 = fmaf(in5, W2.w, v1);
        v0 = fmaf(in6, W3.x, v0); v1 = fmaf(in6, W3.y, v1);
        v0 = fmaf(in7, W3.z, v0); v1 = fmaf(in7, W3.w, v1);
        acc0 = fmaf(w, v0, acc0);
        acc1 = fmaf(w, v1, acc1);
    }
    *o = make_float2(acc0, acc1 * sgn);
}

extern "C" void kernel_launch(void* const* d_in, const int* in_sizes, int n_in,
                              void* d_out, int out_size, void* d_ws, size_t ws_size,
                              hipStream_t stream) {
    const float* input  = (const float*)d_in[0];
    const float* weight = (const float*)d_in[1];
    const float* bias   = (const float*)d_in[2];
    const int*   grid3d = (const int*)  d_in[3];
    const float* rot    = (const float*)d_in[4];
    const float* coord  = (const float*)d_in[5];
    const int*   max_r  = (const int*)  d_in[6];
    float* out = (float*)d_out;

    const int P = in_sizes[5] / 2;        // 13041
    const int B = in_sizes[4] / 9;        // 256
    const int W = in_sizes[1] / 16;       // weight_count

    const size_t wpk_bytes  = (size_t)W * 32;
    const size_t garr_bytes = (size_t)NCELL * 16;
    const size_t in_bytes   = (size_t)B * 16;
    const size_t need_zd    = wpk_bytes + garr_bytes + in_bytes;  // ~72 MB
    const size_t need_bf    = (size_t)W * 36;                     // ~39 MB

    dim3 block(256, 1, 1);

    if (ws_size >= need_zd && P == NXC * NYC) {
        unsigned* wpk = (unsigned*)d_ws;
        int4* garrD = (int4*)((char*)d_ws + wpk_bytes);
        unsigned* inpk = (unsigned*)((char*)d_ws + wpk_bytes + garr_bytes);
        const int nw4 = W * 4;
        const int nbw = (nw4 + 255) / 256;
        const int nbg = (NCELL + 255) / 256;
        const int nin = B * 4;
        const int nbi = (nin + 255) / 256;
        pack_allh<<<nbw + nbg + nbi, block, 0, stream>>>(
            (const float4*)weight, (uint2*)wpk, nw4, nbw,
            grid3d, bias, garrD, NCELL, nbg,
            input, inpk, nin);
        dim3 grid(B, NTX, NTZ);
        svr_dot<<<grid, block, 0, stream>>>(inpk, wpk, garrD, rot, coord,
                                            max_r, out, P);
    } else if (ws_size >= need_bf) {
        unsigned* wpk = (unsigned*)d_ws;
        unsigned* bpk = wpk + (size_t)W * 8;
        const int nw = W * 4;
        pack_w<<<(nw + 255) / 256, block, 0, stream>>>(
            (const float4*)weight, (uint2*)wpk, nw);
        pack_b<<<(W + 255) / 256, block, 0, stream>>>(bias, bpk, W);
        dim3 grid(NBX * B, 1, 1);
        svr_bf16<<<grid, block, 0, stream>>>(input, wpk, bpk, grid3d, rot,
                                             coord, max_r, out, P);
    } else {
        dim3 grid(NBX * B, 1, 1);
        svr_fp32<<<grid, block, 0, stream>>>(input, weight, bias, grid3d, rot,
                                             coord, max_r, out, P);
    }
}

// Round 7
// 213.368 us; speedup vs baseline: 1.0537x; 1.0537x over previous
//
#include <hip/hip_runtime.h>

#define BZ    167              // grid3d_index dims 0/1 (SIZE + 2*MARGIN)
#define BZ2   83               // BZ/2
#define NX    84               // BZ/2 + 1  (last axis)
#define NCELL (BZ * BZ * NX)   // 2,342,676 cells
#define SYC   NX               // +dy stride in cells
#define SZC   (NX * BZ)        // +dz stride in cells
#define NXC   81               // 2D coord grid x extent (SIZE/2+1)
#define NYC   161              // 2D coord grid y extent (SIZE)
#define NTX   21               // ceil(81/4)  tiles in x
#define NTY   41               // ceil(161/4) tiles in y
#define NTILE (NTX * NTY)      // 861 4x4 tiles/batch
#define NBT   216              // ceil(861/4) blocks/batch (4 waves/block)
#define NBX   51               // ceil(13041/256) blocks/batch (fallback tiers)

// ---- bf16 helpers (round-to-nearest-even pack, free unpack) ----
static __device__ __forceinline__ unsigned f2bf(float f) {
    unsigned u = __float_as_uint(f);
    return (u + 0x7FFFu + ((u >> 16) & 1u)) >> 16;
}
static __device__ __forceinline__ float bf_lo(unsigned u) {
    return __uint_as_float(u << 16);
}
static __device__ __forceinline__ float bf_hi(unsigned u) {
    return __uint_as_float(u & 0xFFFF0000u);
}

// ---- f16 pair helpers (for v_dot2_f32_f16 path) ----
typedef _Float16 h2 __attribute__((ext_vector_type(2)));
static __device__ __forceinline__ h2 u2h(unsigned u) {
    union { unsigned u; h2 h; } x; x.u = u; return x.h;
}
static __device__ __forceinline__ unsigned f2h2(float a, float b) {
    union { h2 h; unsigned u; } x;
    x.h.x = (_Float16)a; x.h.y = (_Float16)b;
    return x.u;
}

// ---- fused pre-pass: pack weights fp32->f16 pairs along the input dim
// (dot2 layout), build the COMPACT 8B metadata garr[cell] = (j, bias bf16x2)
// (R6 post-mortem: VALU is slack, so trade z-pair instruction savings for a
// 19 MB vs 37 MB footprint -> better L2 residency on the garr->wpk chain),
// and pack input to f16 pairs.  Weight record layout per j (8 u32):
//   u[2a]   = {f16 w[2a][0], f16 w[2a+1][0]}   (output c=0, dims 2a,2a+1)
//   u[2a+1] = {f16 w[2a][1], f16 w[2a+1][1]}   (output c=1)
// Lane h reads uint4 at j*8+h*4 = dims 4h..4h+3, both outputs. ----
__global__ __launch_bounds__(256) void pack_td(
    const float4* __restrict__ wsrc, uint2* __restrict__ wdst, int nw4, int nbw,
    const int* __restrict__ grid, const float* __restrict__ bias,
    int2* __restrict__ garr, int ncell, int nbg,
    const float* __restrict__ input, unsigned* __restrict__ inpk, int nin)
{
    const int bid = (int)blockIdx.x;
    if (bid < nbw) {
        const int i = bid * 256 + threadIdx.x;
        if (i >= nw4) return;
        // float4 i covers w[2a..2a+1][0..1]: (w[2a][0], w[2a][1], w[2a+1][0], w[2a+1][1])
        const float4 v = wsrc[i];
        wdst[i] = make_uint2(f2h2(v.x, v.z), f2h2(v.y, v.w));
    } else if (bid < nbw + nbg) {
        const int i = (bid - nbw) * 256 + threadIdx.x;
        if (i >= ncell) return;
        const int j = grid[i];
        unsigned bb = 0u;
        if (j >= 0)
            bb = f2bf(bias[2 * j]) | (f2bf(bias[2 * j + 1]) << 16);
        garr[i] = make_int2(j, (int)bb);
    } else {
        const int i = (bid - nbw - nbg) * 256 + threadIdx.x;
        if (i >= nin) return;                  // nin = B*4
        const int b = i >> 2, k = i & 3;
        inpk[i] = f2h2(input[b * 8 + 2 * k], input[b * 8 + 2 * k + 1]);
    }
}

// ===== main kernel: quarter-lane, 4x4 tiles, dot2 inner loop, 8B garr =======
// Best-of-all-rounds recombination:
//   * R5's 1D batch-contiguous block mapping (one XCD runs one batch's tiles
//     back-to-back -> L2 dwell; R6's batch-fastest 3D grid cost ~4us)
//   * R6's v_dot2_f32_f16 inner loop + packed f16 input (VALU ~41us)
//   * COMPACT 8B garr (19 MB) instead of z-paired 16B (37 MB): spends the
//     VALU slack (2 extra gather instrs) on halving metadata footprint ->
//     FETCH and average gather latency drop
__global__ __launch_bounds__(256, 4) void svr_td(
    const unsigned* __restrict__ inpk,    // (B, 4) f16-pair input
    const unsigned* __restrict__ wpk,     // (W, 8) u32 = 16 f16 (dot2 layout)
    const int2*     __restrict__ garr,    // (NCELL): (j, bias bf16x2)
    const float*    __restrict__ rot,     // (B, 3, 3)
    const float*    __restrict__ coord,   // (P, 2)
    const int*      __restrict__ max_r,
    float*          __restrict__ out,     // (B, P, 2)
    int P)
{
    const int m    = blockIdx.x;
    const int xcd  = m & 7;                    // XCD-aware batch striping
    const int slot = m >> 3;
    const int b    = (slot / NBT) * 8 + xcd;
    const int tgrp = slot % NBT;
    const int wid  = threadIdx.x >> 6;         // wave in block (4 waves)
    const int lane = threadIdx.x & 63;
    const int t    = tgrp * 4 + wid;           // tile id
    if (t >= NTILE) return;

    const int q    = lane & 3;                 // quad lane
    const int h    = q & 1;                    // input half
    const int dxl  = q >> 1;                   // this lane's corner dx
    const int sub  = lane >> 2;                // point within 4x4 tile
    const int px   = (t % NTX) * 4 + (sub & 3);
    const int py   = (t / NTX) * 4 + (sub >> 2);
    if (px >= NXC || py >= NYC) return;        // edge tiles: excess lanes exit
    const int p    = py * NXC + px;

    const float2 xy = *(const float2*)(coord + 2 * p);
    const float x = xy.x, y = xy.y;

    const int mr = min(max_r[0], (BZ - 6) / 2);
    const bool valid = (x * x + y * y) <= (float)(mr * mr);

    float2* o = (float2*)(out + ((size_t)b * P + p) * 2);
    if (!valid) {
        if (q == 0) *o = make_float2(0.f, 0.f);
        return;
    }

    const float* R = rot + b * 9;              // block-uniform -> scalar loads
    float cx = fmaf(R[1], y, R[0] * x);
    float cy = fmaf(R[4], y, R[3] * x);
    float cz = fmaf(R[7], y, R[6] * x);

    float sgn = 1.f;
    if (cx < 0.f) { cx = -cx; cy = -cy; cz = -cz; sgn = -1.f; }

    const float fx = floorf(cx), fy = floorf(cy), fz = floorf(cz);
    const float tx = cx - fx, ty = cy - fy, tz = cz - fz;
    const int ix = (int)fx;
    const int iy = (int)fy + BZ2;
    const int iz = (int)fz + BZ2;

    // ---- 4 metadata gathers (dx folded into address); i = dz*2 + dy ----
    const int base0 = (iz * BZ + iy) * NX + ix + dxl;
    int2 Gl[4];
    Gl[0] = garr[base0];                 // (dy0, dz0)
    Gl[1] = garr[base0 + SYC];           // (dy1, dz0)
    Gl[2] = garr[base0 + SZC];           // (dy0, dz1)
    Gl[3] = garr[base0 + SZC + SYC];     // (dy1, dz1)

    // this lane's half of input[b] as f16 pairs (uniform 8B load)
    const uint2 ihu = *(const uint2*)(inpk + b * 4 + h * 2);
    const h2 ihp0 = u2h(ihu.x);            // dims 4h, 4h+1
    const h2 ihp1 = u2h(ihu.y);            // dims 4h+2, 4h+3

    // per-lane corner weights: fixed dx factor x per-i (dy,dz) factor
    const float wxd = dxl ? tx : 1.f - tx;
    float wyz[4];
    wyz[0] = (1.f - ty) * (1.f - tz);
    wyz[1] = ty * (1.f - tz);
    wyz[2] = (1.f - ty) * tz;
    wyz[3] = ty * tz;

    int jj[4]; float wcl[4];
    #pragma unroll
    for (int i = 0; i < 4; ++i) {
        const int j = Gl[i].x;
        wcl[i] = (j >= 0) ? wxd * wyz[i] : 0.f;
        jj[i]  = max(j, 0);
    }

    // ---- 4 record gathers: lane quad covers the 64B x-adjacent record pair
    uint4 U[4];
    #pragma unroll
    for (int i = 0; i < 4; ++i)
        U[i] = *(const uint4*)(wpk + (size_t)jj[i] * 8 + h * 4);

    float acc0 = 0.f, acc1 = 0.f;
    #pragma unroll
    for (int i = 0; i < 4; ++i) {
        const unsigned bb = (unsigned)Gl[i].y;
        // bias contributes once per corner: h==0 lane only
        float v0 = h ? 0.f : bf_lo(bb);
        float v1 = h ? 0.f : bf_hi(bb);
        v0 = __builtin_amdgcn_fdot2(ihp0, u2h(U[i].x), v0, false);
        v0 = __builtin_amdgcn_fdot2(ihp1, u2h(U[i].z), v0, false);
        v1 = __builtin_amdgcn_fdot2(ihp0, u2h(U[i].y), v1, false);
        v1 = __builtin_amdgcn_fdot2(ihp1, u2h(U[i].w), v1, false);
        acc0 = fmaf(wcl[i], v0, acc0);
        acc1 = fmaf(wcl[i], v1, acc1);
    }

    // combine input halves (xor 1) then dx halves (xor 2) within the quad
    acc0 += __shfl_xor(acc0, 1);
    acc1 += __shfl_xor(acc1, 1);
    acc0 += __shfl_xor(acc0, 2);
    acc1 += __shfl_xor(acc1, 2);

    if (q == 0) *o = make_float2(acc0, acc1 * sgn);
}

// ============ fallback tier 2: bf16 weights + separate bias ==================
__global__ __launch_bounds__(256) void pack_w(
    const float4* __restrict__ src, uint2* __restrict__ dst, int n)
{
    const int i = blockIdx.x * 256 + threadIdx.x;
    if (i >= n) return;
    const float4 v = src[i];
    dst[i] = make_uint2(f2bf(v.x) | (f2bf(v.y) << 16),
                        f2bf(v.z) | (f2bf(v.w) << 16));
}
__global__ __launch_bounds__(256) void pack_b(
    const float* __restrict__ bias, unsigned* __restrict__ bpk, int W)
{
    const int j = blockIdx.x * 256 + threadIdx.x;
    if (j >= W) return;
    bpk[j] = f2bf(bias[2 * j]) | (f2bf(bias[2 * j + 1]) << 16);
}

__global__ __launch_bounds__(256) void svr_bf16(
    const float* __restrict__ input, const unsigned* __restrict__ wpk,
    const unsigned* __restrict__ bpk, const int* __restrict__ grid3d,
    const float* __restrict__ rot, const float* __restrict__ coord,
    const int* __restrict__ max_r, float* __restrict__ out, int P)
{
    const int m    = blockIdx.x;
    const int xcd  = m & 7;
    const int slot = m >> 3;
    const int b    = (slot / NBX) * 8 + xcd;
    const int p    = (slot % NBX) * 256 + threadIdx.x;
    if (p >= P) return;

    const float x = coord[2 * p + 0];
    const float y = coord[2 * p + 1];
    const int mr = min(max_r[0], (BZ - 6) / 2);
    const bool valid = (x * x + y * y) <= (float)(mr * mr);
    float2* o = (float2*)(out + ((size_t)b * P + p) * 2);
    if (!valid) { *o = make_float2(0.f, 0.f); return; }

    const float* R = rot + b * 9;
    float cx = fmaf(R[1], y, R[0] * x);
    float cy = fmaf(R[4], y, R[3] * x);
    float cz = fmaf(R[7], y, R[6] * x);
    float sgn = 1.f;
    if (cx < 0.f) { cx = -cx; cy = -cy; cz = -cz; sgn = -1.f; }
    const float fx = floorf(cx), fy = floorf(cy), fz = floorf(cz);
    const float tx = cx - fx, ty = cy - fy, tz = cz - fz;
    const int ix = (int)fx, iy = (int)fy + BZ2, iz = (int)fz + BZ2;

    const float* ib = input + b * 8;
    const float in0 = ib[0], in1 = ib[1], in2 = ib[2], in3 = ib[3];
    const float in4 = ib[4], in5 = ib[5], in6 = ib[6], in7 = ib[7];

    int jj[8]; float wc[8];
    const float wx0 = 1.f - tx, wy0 = 1.f - ty, wz0 = 1.f - tz;
    #pragma unroll
    for (int dz = 0; dz < 2; ++dz)
        #pragma unroll
        for (int dy = 0; dy < 2; ++dy) {
            const int base = ((iz + dz) * BZ + (iy + dy)) * NX + ix;
            #pragma unroll
            for (int dx = 0; dx < 2; ++dx) {
                const int c = dz * 4 + dy * 2 + dx;
                const int j = grid3d[base + dx];
                const float w = (dx ? tx : wx0) * (dy ? ty : wy0) * (dz ? tz : wz0);
                wc[c] = (j >= 0) ? w : 0.f;
                jj[c] = max(j, 0);
            }
        }

    uint4 U0[8], U1[8]; unsigned BB[8];
    #pragma unroll
    for (int c = 0; c < 8; ++c) {
        const uint4* wp = (const uint4*)(wpk + (size_t)jj[c] * 8);
        U0[c] = wp[0]; U1[c] = wp[1]; BB[c] = bpk[jj[c]];
    }

    float acc0 = 0.f, acc1 = 0.f;
    #pragma unroll
    for (int c = 0; c < 8; ++c) {
        const float w = wc[c];
        float v0 = bf_lo(BB[c]), v1 = bf_hi(BB[c]);
        v0 = fmaf(in0, bf_lo(U0[c].x), v0); v1 = fmaf(in0, bf_hi(U0[c].x), v1);
        v0 = fmaf(in1, bf_lo(U0[c].y), v0); v1 = fmaf(in1, bf_hi(U0[c].y), v1);
        v0 = fmaf(in2, bf_lo(U0[c].z), v0); v1 = fmaf(in2, bf_hi(U0[c].z), v1);
        v0 = fmaf(in3, bf_lo(U0[c].w), v0); v1 = fmaf(in3, bf_hi(U0[c].w), v1);
        v0 = fmaf(in4, bf_lo(U1[c].x), v0); v1 = fmaf(in4, bf_hi(U1[c].x), v1);
        v0 = fmaf(in5, bf_lo(U1[c].y), v0); v1 = fmaf(in5, bf_hi(U1[c].y), v1);
        v0 = fmaf(in6, bf_lo(U1[c].z), v0); v1 = fmaf(in6, bf_hi(U1[c].z), v1);
        v0 = fmaf(in7, bf_lo(U1[c].w), v0); v1 = fmaf(in7, bf_hi(U1[c].w), v1);
        acc0 = fmaf(w, v0, acc0);
        acc1 = fmaf(w, v1, acc1);
    }
    *o = make_float2(acc0, acc1 * sgn);
}

// ============ fallback tier 3: direct fp32 (no workspace needed) =============
__global__ __launch_bounds__(256) void svr_fp32(
    const float* __restrict__ input, const float* __restrict__ weight,
    const float* __restrict__ bias, const int* __restrict__ grid3d,
    const float* __restrict__ rot, const float* __restrict__ coord,
    const int* __restrict__ max_r, float* __restrict__ out, int P)
{
    const int m    = blockIdx.x;
    const int xcd  = m & 7;
    const int slot = m >> 3;
    const int b    = (slot / NBX) * 8 + xcd;
    const int p    = (slot % NBX) * 256 + threadIdx.x;
    if (p >= P) return;

    const float x = coord[2 * p + 0];
    const float y = coord[2 * p + 1];
    const int mr = min(max_r[0], (BZ - 6) / 2);
    const bool valid = (x * x + y * y) <= (float)(mr * mr);
    float2* o = (float2*)(out + ((size_t)b * P + p) * 2);
    if (!valid) { *o = make_float2(0.f, 0.f); return; }

    const float* R = rot + b * 9;
    float cx = fmaf(R[1], y, R[0] * x);
    float cy = fmaf(R[4], y, R[3] * x);
    float cz = fmaf(R[7], y, R[6] * x);
    float sgn = 1.f;
    if (cx < 0.f) { cx = -cx; cy = -cy; cz = -cz; sgn = -1.f; }
    const float fx = floorf(cx), fy = floorf(cy), fz = floorf(cz);
    const float tx = cx - fx, ty = cy - fy, tz = cz - fz;
    const int ix = (int)fx, iy = (int)fy + BZ2, iz = (int)fz + BZ2;

    const float* ib = input + b * 8;
    const float in0 = ib[0], in1 = ib[1], in2 = ib[2], in3 = ib[3];
    const float in4 = ib[4], in5 = ib[5], in6 = ib[6], in7 = ib[7];

    int jj[8]; float wc[8];
    const float wx0 = 1.f - tx, wy0 = 1.f - ty, wz0 = 1.f - tz;
    #pragma unroll
    for (int dz = 0; dz < 2; ++dz)
        #pragma unroll
        for (int dy = 0; dy < 2; ++dy) {
            const int base = ((iz + dz) * BZ + (iy + dy)) * NX + ix;
            #pragma unroll
            for (int dx = 0; dx < 2; ++dx) {
                const int c = dz * 4 + dy * 2 + dx;
                const int j = grid3d[base + dx];
                const float w = (dx ? tx : wx0) * (dy ? ty : wy0) * (dz ? tz : wz0);
                wc[c] = (j >= 0) ? w : 0.f;
                jj[c] = max(j, 0);
            }
        }

    float acc0 = 0.f, acc1 = 0.f;
    #pragma unroll
    for (int c = 0; c < 8; ++c) {
        const size_t j = (size_t)jj[c];
        const float4* wp = (const float4*)(weight + j * 16);
        const float4 W0 = wp[0], W1 = wp[1], W2 = wp[2], W3 = wp[3];
        const float2 bb = *(const float2*)(bias + j * 2);
        const float w = wc[c];
        float v0 = bb.x, v1 = bb.y;
        v0 = fmaf(in0, W0.x, v0); v1 = fmaf(in0, W0.y, v1);
        v0 = fmaf(in1, W0.z, v0); v1 = fmaf(in1, W0.w, v1);
        v0 = fmaf(in2, W1.x, v0); v1 = fmaf(in2, W1.y, v1);
        v0 = fmaf(in3, W1.z, v0); v1 = fmaf(in3, W1.w, v1);
        v0 = fmaf(in4, W2.x, v0); v1 = fmaf(in4, W2.y, v1);
        v0 = fmaf(in5, W2.z, v0); v1 = fmaf(in5, W2.w, v1);
        v0 = fmaf(in6, W3.x, v0); v1 = fmaf(in6, W3.y, v1);
        v0 = fmaf(in7, W3.z, v0); v1 = fmaf(in7, W3.w, v1);
        acc0 = fmaf(w, v0, acc0);
        acc1 = fmaf(w, v1, acc1);
    }
    *o = make_float2(acc0, acc1 * sgn);
}

extern "C" void kernel_launch(void* const* d_in, const int* in_sizes, int n_in,
                              void* d_out, int out_size, void* d_ws, size_t ws_size,
                              hipStream_t stream) {
    const float* input  = (const float*)d_in[0];
    const float* weight = (const float*)d_in[1];
    const float* bias   = (const float*)d_in[2];
    const int*   grid3d = (const int*)  d_in[3];
    const float* rot    = (const float*)d_in[4];
    const float* coord  = (const float*)d_in[5];
    const int*   max_r  = (const int*)  d_in[6];
    float* out = (float*)d_out;

    const int P = in_sizes[5] / 2;        // 13041
    const int B = in_sizes[4] / 9;        // 256
    const int W = in_sizes[1] / 16;       // weight_count

    const size_t wpk_bytes  = (size_t)W * 32;
    const size_t garr_bytes = (size_t)NCELL * 8;
    const size_t in_bytes   = (size_t)B * 16;
    const size_t need_td    = wpk_bytes + garr_bytes + in_bytes;  // ~53 MB
    const size_t need_bf    = (size_t)W * 36;                     // ~39 MB

    dim3 block(256, 1, 1);

    if (ws_size >= need_td && P == NXC * NYC) {
        unsigned* wpk = (unsigned*)d_ws;
        int2* garr = (int2*)((char*)d_ws + wpk_bytes);
        unsigned* inpk = (unsigned*)((char*)d_ws + wpk_bytes + garr_bytes);
        const int nw4 = W * 4;
        const int nbw = (nw4 + 255) / 256;
        const int nbg = (NCELL + 255) / 256;
        const int nin = B * 4;
        const int nbi = (nin + 255) / 256;
        pack_td<<<nbw + nbg + nbi, block, 0, stream>>>(
            (const float4*)weight, (uint2*)wpk, nw4, nbw,
            grid3d, bias, garr, NCELL, nbg,
            input, inpk, nin);
        dim3 grid(NBT * B, 1, 1);
        svr_td<<<grid, block, 0, stream>>>(inpk, wpk, garr, rot, coord,
                                           max_r, out, P);
    } else if (ws_size >= need_bf) {
        unsigned* wpk = (unsigned*)d_ws;
        unsigned* bpk = wpk + (size_t)W * 8;
        const int nw = W * 4;
        pack_w<<<(nw + 255) / 256, block, 0, stream>>>(
            (const float4*)weight, (uint2*)wpk, nw);
        pack_b<<<(W + 255) / 256, block, 0, stream>>>(bias, bpk, W);
        dim3 grid(NBX * B, 1, 1);
        svr_bf16<<<grid, block, 0, stream>>>(input, wpk, bpk, grid3d, rot,
                                             coord, max_r, out, P);
    } else {
        dim3 grid(NBX * B, 1, 1);
        svr_fp32<<<grid, block, 0, stream>>>(input, weight, bias, grid3d, rot,
                                             coord, max_r, out, P);
    }
}